// Round 1
// baseline (131.308 us; speedup 1.0000x reference)
//
#include <hip/hip_runtime.h>
#include <math.h>

#define NROWS 16384
#define NCOLS 10000
#define NV4   (NCOLS / 4)   // 2500 float4 per row

__device__ __forceinline__ float block_reduce_sum(float s) {
    // wave (64-lane) butterfly
    #pragma unroll
    for (int off = 32; off; off >>= 1) s += __shfl_down(s, off, 64);
    __shared__ float wsum[4];
    int lane = threadIdx.x & 63;
    int wid  = threadIdx.x >> 6;
    if (lane == 0) wsum[wid] = s;
    __syncthreads();
    float total = 0.f;
    if (threadIdx.x == 0) {
        total = wsum[0] + wsum[1] + wsum[2] + wsum[3];
    }
    return total;  // valid in thread 0 only
}

__global__ __launch_bounds__(256) void ams_row_kernel(
        const float* __restrict__ logits,
        const int*   __restrict__ targets,
        float*       __restrict__ row_loss) {
    const int row = blockIdx.x;
    const float* rp = logits + (size_t)row * NCOLS;
    const float4* rp4 = reinterpret_cast<const float4*>(rp);

    float s = 0.f;
    for (int i = threadIdx.x; i < NV4; i += 256) {
        float4 v = rp4[i];
        s += __expf(v.x) + __expf(v.y) + __expf(v.z) + __expf(v.w);
    }
    float total = block_reduce_sum(s);
    if (threadIdx.x == 0) {
        const float expm = __expf(0.4f);          // exp(M)
        float num = rp[targets[row]];             // target logit
        float en  = __expf(num);
        float denom = en + (total - en) * expm;
        row_loss[row] = num - __logf(denom + 1e-10f);
    }
}

__global__ __launch_bounds__(256) void ams_final_kernel(
        const float* __restrict__ row_loss,
        float*       __restrict__ out) {
    float s = 0.f;
    for (int i = threadIdx.x; i < NROWS; i += 256) s += row_loss[i];
    float total = block_reduce_sum(s);
    if (threadIdx.x == 0) {
        out[0] = -total / (float)NROWS;
    }
}

extern "C" void kernel_launch(void* const* d_in, const int* in_sizes, int n_in,
                              void* d_out, int out_size, void* d_ws, size_t ws_size,
                              hipStream_t stream) {
    const float* logits  = (const float*)d_in[0];
    const int*   targets = (const int*)d_in[1];
    float*       out     = (float*)d_out;
    float*       row_loss = (float*)d_ws;   // NROWS floats = 64 KB scratch

    ams_row_kernel<<<NROWS, 256, 0, stream>>>(logits, targets, row_loss);
    ams_final_kernel<<<1, 256, 0, stream>>>(row_loss, out);
}

// Round 3
// 115.976 us; speedup vs baseline: 1.1322x; 1.1322x over previous
//
#include <hip/hip_runtime.h>
#include <math.h>

#define NROWS 16384
#define NCOLS 10000
#define NV4   (NCOLS / 4)      // 2500 float4 per row
#define TPB   256
#define FULL_ITERS (NV4 / TPB) // 9
#define TAIL       (NV4 % TPB) // 196

typedef float f32x4 __attribute__((ext_vector_type(4)));

__device__ __forceinline__ float block_reduce_sum(float s) {
    #pragma unroll
    for (int off = 32; off; off >>= 1) s += __shfl_down(s, off, 64);
    __shared__ float wsum[4];
    int lane = threadIdx.x & 63;
    int wid  = threadIdx.x >> 6;
    if (lane == 0) wsum[wid] = s;
    __syncthreads();
    float total = 0.f;
    if (threadIdx.x == 0) total = wsum[0] + wsum[1] + wsum[2] + wsum[3];
    return total;  // valid in thread 0 only
}

__global__ __launch_bounds__(TPB) void ams_row_kernel(
        const float* __restrict__ logits,
        const int*   __restrict__ targets,
        float*       __restrict__ row_loss) {
    const int row = blockIdx.x;
    const float* rp = logits + (size_t)row * NCOLS;
    const f32x4* rp4 = reinterpret_cast<const f32x4*>(rp) + threadIdx.x;

    // Issue all loads up front (compile-time trip count -> full unroll,
    // 9 global_load_dwordx4 in flight before first waitcnt).
    f32x4 v[FULL_ITERS];
    #pragma unroll
    for (int k = 0; k < FULL_ITERS; ++k)
        v[k] = __builtin_nontemporal_load(rp4 + k * TPB);

    f32x4 vt;
    const bool has_tail = (threadIdx.x < TAIL);
    if (has_tail)
        vt = __builtin_nontemporal_load(rp4 + FULL_ITERS * TPB);

    float acc0 = 0.f, acc1 = 0.f, acc2 = 0.f, acc3 = 0.f;
    #pragma unroll
    for (int k = 0; k < FULL_ITERS; ++k) {
        acc0 += __expf(v[k].x);
        acc1 += __expf(v[k].y);
        acc2 += __expf(v[k].z);
        acc3 += __expf(v[k].w);
    }
    if (has_tail) {
        acc0 += __expf(vt.x);
        acc1 += __expf(vt.y);
        acc2 += __expf(vt.z);
        acc3 += __expf(vt.w);
    }
    float s = (acc0 + acc1) + (acc2 + acc3);

    float total = block_reduce_sum(s);
    if (threadIdx.x == 0) {
        const float expm = __expf(0.4f);          // exp(M)
        float num = rp[targets[row]];             // target logit (L2-hot)
        float en  = __expf(num);
        float denom = en + (total - en) * expm;
        row_loss[row] = num - __logf(denom + 1e-10f);
    }
}

__global__ __launch_bounds__(256) void ams_final_kernel(
        const float* __restrict__ row_loss,
        float*       __restrict__ out) {
    float s = 0.f;
    for (int i = threadIdx.x; i < NROWS; i += 256) s += row_loss[i];
    float total = block_reduce_sum(s);
    if (threadIdx.x == 0) out[0] = -total / (float)NROWS;
}

extern "C" void kernel_launch(void* const* d_in, const int* in_sizes, int n_in,
                              void* d_out, int out_size, void* d_ws, size_t ws_size,
                              hipStream_t stream) {
    const float* logits   = (const float*)d_in[0];
    const int*   targets  = (const int*)d_in[1];
    float*       out      = (float*)d_out;
    float*       row_loss = (float*)d_ws;   // NROWS floats = 64 KB scratch

    ams_row_kernel<<<NROWS, TPB, 0, stream>>>(logits, targets, row_loss);
    ams_final_kernel<<<1, 256, 0, stream>>>(row_loss, out);
}